// Round 15
// baseline (152.463 us; speedup 1.0000x reference)
//
#include <hip/hip_runtime.h>
#include <stdint.h>
#include <math.h>

#define NB 16
#define NS 512
#define NH 12
#define ND 64
#define NE 768
#define NF 768

typedef __attribute__((ext_vector_type(4))) float  f32x4;
typedef __attribute__((ext_vector_type(8))) short  bf16x8;

#define AS1(p) ((const __attribute__((address_space(1))) unsigned int*)(p))
#define AS3(p) ((__attribute__((address_space(3))) unsigned int*)(p))

__device__ __forceinline__ short f2bf(float f) {
    unsigned u = __builtin_bit_cast(unsigned, f);
    u += 0x7FFFu + ((u >> 16) & 1u);
    return (short)(u >> 16);
}
__device__ __forceinline__ float bf2f(short s) {
    unsigned u = ((unsigned)(unsigned short)s) << 16;
    return __builtin_bit_cast(float, u);
}
__device__ __forceinline__ unsigned pkbf2(float a, float b) {
    return (unsigned)(unsigned short)f2bf(a) | ((unsigned)(unsigned short)f2bf(b) << 16);
}

#define MFMA16(a, b, c) __builtin_amdgcn_mfma_f32_16x16x32_bf16((a), (b), (c), 0, 0, 0)

// swizzled LDS tile access: tiles are [rows][64] bf16 (128 B rows), byte ^= ((row&7)<<4)
__device__ __forceinline__ bf16x8 lds_rd8(const short* base, int row, int cb) {
    return *(const bf16x8*)((const char*)base + (((row) * 128 + (cb)) ^ (((row) & 7) << 4)));
}

// ---------------- K1: merged front-end ----------------
// bid 0..63: rope tables | bid 64: mask probe | bid 65..640: weight transpose+convert
// bid 641..3712: x fp32->bf16 convert.
__global__ __launch_bounds__(256) void prep_all_kernel(
    const float* __restrict__ x, short* __restrict__ xb,
    const float* __restrict__ Wq, const float* __restrict__ Wk,
    const float* __restrict__ Wv, const float* __restrict__ Wo,
    short* __restrict__ Wqt, short* __restrict__ Wkt,
    short* __restrict__ Wvt, short* __restrict__ Wot,
    float* __restrict__ cos_t, float* __restrict__ sin_t,
    const unsigned char* __restrict__ m, int* __restrict__ flag) {
    const int bid = blockIdx.x;
    if (bid < 64) {
        int i = bid * 256 + threadIdx.x;
        int p = i >> 5, j = i & 31;
        float inv_freq = powf(10000.0f, -(float)j / 32.0f);
        float ang = (float)p * inv_freq;
        cos_t[i] = cosf(ang);
        sin_t[i] = sinf(ang);
        return;
    }
    if (bid == 64) {   // probe: byte storage has nonzero bytes at offsets %4 != 0
        __shared__ int any;
        if (threadIdx.x == 0) any = 0;
        __syncthreads();
        int acc = 0;
        for (int i = threadIdx.x; i < NB * NS; i += 256)
            if ((i & 3) && m[i]) acc = 1;
        if (acc) atomicOr(&any, 1);
        __syncthreads();
        if (threadIdx.x == 0) *flag = any;   // 1 = byte storage, 0 = int32 storage
        return;
    }
    if (bid < 641) {   // weight transpose: W[k][n] fp32 -> Wt[n][k] bf16
        int idx = bid - 65;
        int zz = idx / 144, r2 = idx % 144;
        const float* W  = (zz == 0) ? Wq  : (zz == 1) ? Wk  : (zz == 2) ? Wv  : Wo;
        short*       Wt = (zz == 0) ? Wqt : (zz == 1) ? Wkt : (zz == 2) ? Wvt : Wot;
        const int k0 = (r2 / 12) * 64, n0 = (r2 % 12) * 64;
        __shared__ float t[64][65];
        for (int u = threadIdx.x; u < 4096; u += 256) {
            int r = u >> 6, c = u & 63;
            t[r][c] = W[(size_t)(k0 + r) * 768 + n0 + c];
        }
        __syncthreads();
        for (int u = threadIdx.x; u < 4096; u += 256) {
            int c = u >> 6, r = u & 63;
            Wt[(size_t)(n0 + c) * 768 + k0 + r] = f2bf(t[r][c]);
        }
        return;
    }
    int i = ((bid - 641) * 256 + threadIdx.x) * 8;   // convert x
    float4 a = *(const float4*)&x[i];
    float4 b = *(const float4*)&x[i + 4];
    bf16x8 r = { f2bf(a.x), f2bf(a.y), f2bf(a.z), f2bf(a.w),
                 f2bf(b.x), f2bf(b.y), f2bf(b.z), f2bf(b.w) };
    *(bf16x8*)&xb[i] = r;
}

// ---------------- K4: QKV projection GEMM (64x64 tile, 2-phase, XCD-swizzled) ----------------
// flat grid 4608: xcd owns 16 m-panels x 36 (n,z) tiles. LDS 32 KB -> 5 blocks/CU.
// 4 waves stacked on m (16 rows x 64 cols each), acc[4], 8 MFMA/phase/wave.
// z==1 (K) also writes roped K (pairs acc[j]/acc[j+2]); z==2 (V) writes (b,h,d,s).
__global__ __launch_bounds__(256) void gemm_qkv_kernel(const short* __restrict__ xb,
    const short* __restrict__ Wqt, const short* __restrict__ Wkt, const short* __restrict__ Wvt,
    const float* __restrict__ cos_t, const float* __restrict__ sin_t,
    short* __restrict__ qo, short* __restrict__ ko, short* __restrict__ kpo,
    short* __restrict__ vto) {
    const int id = blockIdx.x;
    const int xcd = id & 7, rest = id >> 3;   // rest 0..575
    const int mq = rest / 36;                 // 0..15
    const int nz = rest % 36;
    const int z  = nz / 12;
    const int n0 = (nz % 12) * 64;
    const int m0 = (xcd * 16 + mq) * 64;
    const short* Bt = (z == 0) ? Wqt : (z == 1) ? Wkt : Wvt;
    short*       O  = (z == 0) ? qo  : (z == 1) ? ko  : vto;
    __shared__ short As[2][64 * 64], Bs[2][64 * 64];   // 32 KB double-buffered
    const int tid = threadIdx.x, lane = tid & 63, wave = tid >> 6;
    const int g = lane >> 4, l15 = lane & 15;
    f32x4 acc[4];
    #pragma unroll
    for (int j = 0; j < 4; ++j) acc[j] = (f32x4){0.f, 0.f, 0.f, 0.f};

    auto STAGE = [&](short* Ad, short* Bd, int kt) {   // 4 glds/wave
        const char* Asrc = (const char*)(xb + (size_t)m0 * 768 + kt * 64);
        const char* Bsrc = (const char*)(Bt + (size_t)n0 * 768 + kt * 64);
        #pragma unroll
        for (int p = 0; p < 2; ++p) {
            int dstoff = (wave * 2 + p) * 1024;
            int off = dstoff + lane * 16;
            int row = off >> 7, slot = off & 127;
            int srcs = slot ^ ((row & 7) << 4);
            __builtin_amdgcn_global_load_lds(AS1(Asrc + (size_t)row * 1536 + srcs),
                                             AS3((char*)Ad + dstoff), 16, 0, 0);
            __builtin_amdgcn_global_load_lds(AS1(Bsrc + (size_t)row * 1536 + srcs),
                                             AS3((char*)Bd + dstoff), 16, 0, 0);
        }
    };
    auto COMPUTE = [&](const short* Asb, const short* Bsb) {
        __builtin_amdgcn_s_setprio(1);
        #pragma unroll
        for (int h2 = 0; h2 < 2; ++h2) {
            const int cb = h2 * 64 + g * 16;
            bf16x8 af = lds_rd8(Asb, wave * 16 + l15, cb);
            bf16x8 bfr[4];
            #pragma unroll
            for (int j = 0; j < 4; ++j)
                bfr[j] = lds_rd8(Bsb, j * 16 + l15, cb);
            #pragma unroll
            for (int j = 0; j < 4; ++j)
                acc[j] = MFMA16(af, bfr[j], acc[j]);
        }
        __builtin_amdgcn_s_setprio(0);
    };

    STAGE(As[0], Bs[0], 0);
    asm volatile("s_waitcnt vmcnt(0)" ::: "memory");
    __builtin_amdgcn_s_barrier();
    int cur = 0;
    for (int kt = 0; kt < 11; ++kt) {
        STAGE(As[cur ^ 1], Bs[cur ^ 1], kt + 1);   // next-tile loads in flight
        COMPUTE(As[cur], Bs[cur]);                 // hide load latency under MFMA
        asm volatile("s_waitcnt vmcnt(0)" ::: "memory");
        __builtin_amdgcn_s_barrier();
        cur ^= 1;
    }
    COMPUTE(As[cur], Bs[cur]);

    const int hh = n0 >> 6;   // head index (tile = one head)
    #pragma unroll
    for (int r = 0; r < 4; ++r) {
        int mm = m0 + wave * 16 + g * 4 + r;
        int bb = mm >> 9, ss = mm & 511;
        if (z == 2) {   // V -> (b,h,d,s)
            #pragma unroll
            for (int j = 0; j < 4; ++j) {
                int dd = j * 16 + l15;
                O[(((size_t)bb * NH + hh) * ND + dd) * NS + ss] = f2bf(acc[j][r]);
            }
        } else {
            size_t base = (((size_t)bb * NH + hh) * NS + ss) * ND;
            #pragma unroll
            for (int j = 0; j < 4; ++j)
                O[base + j * 16 + l15] = f2bf(acc[j][r]);
            if (z == 1) {   // roped K from pairs (j, j+2) = (d, d+32)
                #pragma unroll
                for (int p2 = 0; p2 < 2; ++p2) {
                    int jf = p2 * 16 + l15;
                    float c = cos_t[ss * 32 + jf], s = sin_t[ss * 32 + jf];
                    float t1 = acc[p2][r], t2 = acc[p2 + 2][r];
                    kpo[base + jf]      = f2bf(t1 * c - t2 * s);
                    kpo[base + 32 + jf] = f2bf(t1 * s + t2 * c);
                }
            }
        }
    }
}

// ---------------- K6: fused chain-aware flash attention (T14 async-STAGE split) ----------------
__global__ __launch_bounds__(256) void attn_fused_kernel(
    const short* __restrict__ qr, const short* __restrict__ kr, const short* __restrict__ kp,
    const short* __restrict__ vt,
    const float* __restrict__ cos_t, const float* __restrict__ sin_t,
    const int* __restrict__ chain, const void* __restrict__ amask,
    const int* __restrict__ mflag, short* __restrict__ aout) {
    const int lid = blockIdx.x;
    const int xcd = lid & 7, idx = lid >> 3;
    const int qt = idx & 7, bhl = idx >> 3;
    const int bh = xcd * 24 + bhl;
    const int b = bh / 12, h = bh - (bh / 12) * 12;
    const int q0 = qt * 64;

    __shared__ short Kr_s[4096];
    __shared__ short Kp_s[4096];
    __shared__ short Vt_s[4096];
    __shared__ short P_s[4096];
    __shared__ int   ck_a[512];
    __shared__ float kb_a[512];

    const int tid = threadIdx.x, lane = tid & 63, wave = tid >> 6;
    const int g = lane >> 4, l15 = lane & 15;
    const int m_u8 = *mflag;
    const size_t bhNS = (size_t)bh * NS;
    const float SC = 0.18033688011f;   // 0.125 * log2(e)

    for (int u = tid; u < NS; u += 256) {
        int gidx = b * NS + u;
        ck_a[u] = chain[gidx];
        int ok = m_u8 ? (int)((const unsigned char*)amask)[gidx] : ((const int*)amask)[gidx];
        kb_a[u] = ok ? 0.f : -INFINITY;
    }
    const char* qrsC = (const char*)(qr + (bhNS + q0) * ND);
    #pragma unroll
    for (int p = 0; p < 2; ++p) {
        int dstoff = (wave * 2 + p) * 1024;
        int off = dstoff + lane * 16;
        int row = off >> 7, slot = off & 127;
        int srcs = slot ^ ((row & 7) << 4);
        __builtin_amdgcn_global_load_lds(AS1(qrsC + (size_t)row * 128 + srcs),
                                         AS3((char*)Kr_s + dstoff), 16, 0, 0);
    }
    __syncthreads();
    const int qrow = wave * 16 + l15;
    bf16x8 fqr0 = lds_rd8(Kr_s, qrow, g * 16);
    bf16x8 fqr1 = lds_rd8(Kr_s, qrow, 64 + g * 16);
    bf16x8 fqp0, fqp1;
    {
        int pos = q0 + qrow;
        float4 c0 = *(const float4*)&cos_t[pos * 32 + g * 8];
        float4 c1 = *(const float4*)&cos_t[pos * 32 + g * 8 + 4];
        float4 s0 = *(const float4*)&sin_t[pos * 32 + g * 8];
        float4 s1 = *(const float4*)&sin_t[pos * 32 + g * 8 + 4];
        float cc[8] = {c0.x, c0.y, c0.z, c0.w, c1.x, c1.y, c1.z, c1.w};
        float ss[8] = {s0.x, s0.y, s0.z, s0.w, s1.x, s1.y, s1.z, s1.w};
        #pragma unroll
        for (int j = 0; j < 8; ++j) {
            float t1 = bf2f(fqr0[j]), t2 = bf2f(fqr1[j]);
            fqp0[j] = f2bf(t1 * cc[j] - t2 * ss[j]);
            fqp1[j] = f2bf(t1 * ss[j] + t2 * cc[j]);
        }
    }
    const int cqv = ck_a[q0 + qrow];

    float m_run = -INFINITY, l_run = 0.f;
    f32x4 accO[4];
    #pragma unroll
    for (int t = 0; t < 4; ++t) accO[t] = (f32x4){0.f, 0.f, 0.f, 0.f};

    const char* krC = (const char*)(kr + bhNS * ND);
    const char* kpC = (const char*)(kp + bhNS * ND);
    const char* vtC = (const char*)(vt + bhNS * ND);

    int off_[2], row_[2], srcs_[2];
    #pragma unroll
    for (int p = 0; p < 2; ++p) {
        int dstoff = (wave * 2 + p) * 1024;
        off_[p]  = dstoff + lane * 16;
        row_[p]  = off_[p] >> 7;
        srcs_[p] = (off_[p] & 127) ^ ((row_[p] & 7) << 4);
    }
    uint4 rK0, rK1, rP0, rP1, rV0, rV1;   // named (rule #20: static indexing)
    auto LOADREGS = [&](int kv) {
        const int k0s = kv * 64;
        rK0 = *(const uint4*)(krC + (size_t)(k0s + row_[0]) * 128 + srcs_[0]);
        rK1 = *(const uint4*)(krC + (size_t)(k0s + row_[1]) * 128 + srcs_[1]);
        rP0 = *(const uint4*)(kpC + (size_t)(k0s + row_[0]) * 128 + srcs_[0]);
        rP1 = *(const uint4*)(kpC + (size_t)(k0s + row_[1]) * 128 + srcs_[1]);
        rV0 = *(const uint4*)(vtC + (size_t)row_[0] * 1024 + (size_t)k0s * 2 + srcs_[0]);
        rV1 = *(const uint4*)(vtC + (size_t)row_[1] * 1024 + (size_t)k0s * 2 + srcs_[1]);
    };
    auto WRITELDS = [&]() {
        *(uint4*)((char*)Kr_s + off_[0]) = rK0;
        *(uint4*)((char*)Kr_s + off_[1]) = rK1;
        *(uint4*)((char*)Kp_s + off_[0]) = rP0;
        *(uint4*)((char*)Kp_s + off_[1]) = rP1;
        *(uint4*)((char*)Vt_s + off_[0]) = rV0;
        *(uint4*)((char*)Vt_s + off_[1]) = rV1;
    };

    LOADREGS(0);
    __syncthreads();   // all waves done reading Q frags from Kr_s

    for (int kv = 0; kv < 8; ++kv) {
        const int k0s = kv * 64;
        WRITELDS();
        __syncthreads();
        if (kv < 7) LOADREGS(kv + 1);   // issue next-tile loads; no wait

        float pm[4][4];
        float tm = -INFINITY;
        __builtin_amdgcn_s_setprio(1);
        #pragma unroll
        for (int t = 0; t < 4; ++t) {
            bf16x8 akr0 = lds_rd8(Kr_s, t * 16 + l15, g * 16);
            bf16x8 akr1 = lds_rd8(Kr_s, t * 16 + l15, 64 + g * 16);
            bf16x8 akp0 = lds_rd8(Kp_s, t * 16 + l15, g * 16);
            bf16x8 akp1 = lds_rd8(Kp_s, t * 16 + l15, 64 + g * 16);
            f32x4 sr = (f32x4){0.f, 0.f, 0.f, 0.f};
            f32x4 sp = (f32x4){0.f, 0.f, 0.f, 0.f};
            sr = MFMA16(akr0, fqr0, sr);
            sr = MFMA16(akr1, fqr1, sr);
            sp = MFMA16(akp0, fqp0, sp);
            sp = MFMA16(akp1, fqp1, sp);
            int4   ck4 = *(const int4*)&ck_a[k0s + t * 16 + g * 4];
            float4 kb4 = *(const float4*)&kb_a[k0s + t * 16 + g * 4];
            const int   ckk[4] = {ck4.x, ck4.y, ck4.z, ck4.w};
            const float kbb[4] = {kb4.x, kb4.y, kb4.z, kb4.w};
            #pragma unroll
            for (int r = 0; r < 4; ++r) {
                float sv = (cqv == ckk[r]) ? sp[r] : sr[r];
                sv = sv * SC + kbb[r];
                pm[t][r] = sv;
                tm = fmaxf(tm, sv);
            }
        }
        __builtin_amdgcn_s_setprio(0);

        tm = fmaxf(tm, __shfl_xor(tm, 16));
        tm = fmaxf(tm, __shfl_xor(tm, 32));
        bool skip = __all(tm - m_run <= 8.f);
        float mnew, fac;
        if (skip) { mnew = m_run; fac = 1.f; }
        else      { mnew = fmaxf(m_run, tm); fac = exp2f(m_run - mnew); }
        float psum = 0.f;
        if (mnew == -INFINITY) {
            #pragma unroll
            for (int t = 0; t < 4; ++t)
                #pragma unroll
                for (int r = 0; r < 4; ++r) pm[t][r] = 0.f;
            fac = 1.f;
        } else {
            #pragma unroll
            for (int t = 0; t < 4; ++t)
                #pragma unroll
                for (int r = 0; r < 4; ++r) {
                    float p = exp2f(pm[t][r] - mnew);
                    pm[t][r] = p;
                    psum += p;
                }
        }
        psum += __shfl_xor(psum, 16);
        psum += __shfl_xor(psum, 32);
        l_run = l_run * fac + psum;
        m_run = mnew;

        char* pwave = (char*)P_s + wave * 2048;
        int psw = (l15 & 7) << 4;
        #pragma unroll
        for (int t = 0; t < 4; ++t) {
            unsigned u0 = pkbf2(pm[t][0], pm[t][1]);
            unsigned u1 = pkbf2(pm[t][2], pm[t][3]);
            uint2 pk = {u0, u1};
            *(uint2*)(pwave + ((l15 * 128 + t * 32 + g * 8) ^ psw)) = pk;
        }
        if (!skip) {
            float f4[4];
            #pragma unroll
            for (int r = 0; r < 4; ++r) f4[r] = __shfl(fac, g * 4 + r);
            #pragma unroll
            for (int t = 0; t < 4; ++t) {
                f32x4 a = accO[t];
                a[0] *= f4[0]; a[1] *= f4[1]; a[2] *= f4[2]; a[3] *= f4[3];
                accO[t] = a;
            }
        }
        bf16x8 pa0 = *(const bf16x8*)(pwave + ((l15 * 128 + g * 16) ^ psw));
        bf16x8 pa1 = *(const bf16x8*)(pwave + ((l15 * 128 + 64 + g * 16) ^ psw));
        __builtin_amdgcn_s_setprio(1);
        #pragma unroll
        for (int dt = 0; dt < 4; ++dt) {
            bf16x8 vb0 = lds_rd8(Vt_s, dt * 16 + l15, g * 16);
            bf16x8 vb1 = lds_rd8(Vt_s, dt * 16 + l15, 64 + g * 16);
            accO[dt] = MFMA16(pa0, vb0, accO[dt]);
            accO[dt] = MFMA16(pa1, vb1, accO[dt]);
        }
        __builtin_amdgcn_s_setprio(0);
        __syncthreads();   // all waves done reading tiles before next WRITELDS
    }

    float inv[4];
    #pragma unroll
    for (int r = 0; r < 4; ++r) {
        float lv = __shfl(l_run, g * 4 + r);
        inv[r] = (lv > 0.f) ? 1.f / lv : 0.f;
    }
    #pragma unroll
    for (int dt = 0; dt < 4; ++dt)
        #pragma unroll
        for (int r = 0; r < 4; ++r) {
            int row = b * NS + q0 + wave * 16 + g * 4 + r;
            aout[(size_t)row * NF + h * ND + dt * 16 + l15] = f2bf(accO[dt][r] * inv[r]);
        }
}

// ---------------- K7: output projection GEMM (64x64 tile, 2-phase, XCD-swizzled) ----------------
// flat grid 1536: xcd owns 16 m-panels x 12 n-tiles. LDS 32 KB -> 5 blocks/CU.
__global__ __launch_bounds__(256) void gemm_out_kernel(const short* __restrict__ A,
    const short* __restrict__ Wot, float* __restrict__ out) {
    const int id = blockIdx.x;
    const int xcd = id & 7, rest = id >> 3;   // rest 0..191
    const int mq = rest / 12;                 // 0..15
    const int n0 = (rest % 12) * 64;
    const int m0 = (xcd * 16 + mq) * 64;
    __shared__ short As[2][64 * 64], Bs[2][64 * 64];   // 32 KB
    const int tid = threadIdx.x, lane = tid & 63, wave = tid >> 6;
    const int g = lane >> 4, l15 = lane & 15;
    f32x4 acc[4];
    #pragma unroll
    for (int j = 0; j < 4; ++j) acc[j] = (f32x4){0.f, 0.f, 0.f, 0.f};

    auto STAGE = [&](short* Ad, short* Bd, int kt) {
        const char* Asrc = (const char*)(A   + (size_t)m0 * 768 + kt * 64);
        const char* Bsrc = (const char*)(Wot + (size_t)n0 * 768 + kt * 64);
        #pragma unroll
        for (int p = 0; p < 2; ++p) {
            int dstoff = (wave * 2 + p) * 1024;
            int off = dstoff + lane * 16;
            int row = off >> 7, slot = off & 127;
            int srcs = slot ^ ((row & 7) << 4);
            __builtin_amdgcn_global_load_lds(AS1(Asrc + (size_t)row * 1536 + srcs),
                                             AS3((char*)Ad + dstoff), 16, 0, 0);
            __builtin_amdgcn_global_load_lds(AS1(Bsrc + (size_t)row * 1536 + srcs),
                                             AS3((char*)Bd + dstoff), 16, 0, 0);
        }
    };
    auto COMPUTE = [&](const short* Asb, const short* Bsb) {
        __builtin_amdgcn_s_setprio(1);
        #pragma unroll
        for (int h2 = 0; h2 < 2; ++h2) {
            const int cb = h2 * 64 + g * 16;
            bf16x8 af = lds_rd8(Asb, wave * 16 + l15, cb);
            bf16x8 bfr[4];
            #pragma unroll
            for (int j = 0; j < 4; ++j)
                bfr[j] = lds_rd8(Bsb, j * 16 + l15, cb);
            #pragma unroll
            for (int j = 0; j < 4; ++j)
                acc[j] = MFMA16(af, bfr[j], acc[j]);
        }
        __builtin_amdgcn_s_setprio(0);
    };

    STAGE(As[0], Bs[0], 0);
    asm volatile("s_waitcnt vmcnt(0)" ::: "memory");
    __builtin_amdgcn_s_barrier();
    int cur = 0;
    for (int kt = 0; kt < 11; ++kt) {
        STAGE(As[cur ^ 1], Bs[cur ^ 1], kt + 1);
        COMPUTE(As[cur], Bs[cur]);
        asm volatile("s_waitcnt vmcnt(0)" ::: "memory");
        __builtin_amdgcn_s_barrier();
        cur ^= 1;
    }
    COMPUTE(As[cur], Bs[cur]);

    #pragma unroll
    for (int r = 0; r < 4; ++r) {
        int mm = m0 + wave * 16 + g * 4 + r;
        #pragma unroll
        for (int j = 0; j < 4; ++j) {
            int n = n0 + j * 16 + l15;
            out[(size_t)mm * NE + n] = acc[j][r];
        }
    }
}

extern "C" void kernel_launch(void* const* d_in, const int* in_sizes, int n_in,
                              void* d_out, int out_size, void* d_ws, size_t ws_size,
                              hipStream_t stream) {
    const float* x     = (const float*)d_in[0];
    const int*   chain = (const int*)d_in[1];
    const void*  amask = d_in[2];
    const float* Wq = (const float*)d_in[3];
    const float* Wk = (const float*)d_in[4];
    const float* Wv = (const float*)d_in[5];
    const float* Wo = (const float*)d_in[6];
    float* out = (float*)d_out;

    const size_t QSZ = (size_t)NB * NH * NS * ND;
    char* w = (char*)d_ws;
    float* cos_t = (float*)w;  w += (size_t)NS * 32 * 4;
    float* sin_t = (float*)w;  w += (size_t)NS * 32 * 4;
    int*   mflag = (int*)w;    w += 256;
    short* xb    = (short*)w;  w += (size_t)8192 * 768 * 2;  // reused as aout later
    short* Wqt   = (short*)w;  w += (size_t)768 * 768 * 2;
    short* Wkt   = (short*)w;  w += (size_t)768 * 768 * 2;
    short* Wvt   = (short*)w;  w += (size_t)768 * 768 * 2;
    short* Wot   = (short*)w;  w += (size_t)768 * 768 * 2;
    short* q_raw = (short*)w;  w += QSZ * 2;
    short* k_raw = (short*)w;  w += QSZ * 2;
    short* k_rop = (short*)w;  w += QSZ * 2;
    short* vtr   = (short*)w;  w += QSZ * 2;
    short* aout  = xb;   // lifetime-disjoint reuse

    prep_all_kernel<<<dim3(3713), dim3(256), 0, stream>>>(x, xb, Wq, Wk, Wv, Wo,
                                                          Wqt, Wkt, Wvt, Wot,
                                                          cos_t, sin_t,
                                                          (const unsigned char*)amask, mflag);
    gemm_qkv_kernel<<<dim3(4608), dim3(256), 0, stream>>>(xb, Wqt, Wkt, Wvt, cos_t, sin_t,
                                                          q_raw, k_raw, k_rop, vtr);
    attn_fused_kernel<<<dim3(1536), dim3(256), 0, stream>>>(q_raw, k_raw, k_rop, vtr,
                                                            cos_t, sin_t, chain, amask, mflag, aout);
    gemm_out_kernel<<<dim3(1536), dim3(256), 0, stream>>>(aout, Wot, out);
}

// Round 16
// 142.928 us; speedup vs baseline: 1.0667x; 1.0667x over previous
//
#include <hip/hip_runtime.h>
#include <stdint.h>
#include <math.h>

#define NB 16
#define NS 512
#define NH 12
#define ND 64
#define NE 768
#define NF 768

typedef __attribute__((ext_vector_type(4))) float  f32x4;
typedef __attribute__((ext_vector_type(8))) short  bf16x8;

#define AS1(p) ((const __attribute__((address_space(1))) unsigned int*)(p))
#define AS3(p) ((__attribute__((address_space(3))) unsigned int*)(p))

__device__ __forceinline__ short f2bf(float f) {
    unsigned u = __builtin_bit_cast(unsigned, f);
    u += 0x7FFFu + ((u >> 16) & 1u);
    return (short)(u >> 16);
}
__device__ __forceinline__ float bf2f(short s) {
    unsigned u = ((unsigned)(unsigned short)s) << 16;
    return __builtin_bit_cast(float, u);
}
__device__ __forceinline__ unsigned pkbf2(float a, float b) {
    return (unsigned)(unsigned short)f2bf(a) | ((unsigned)(unsigned short)f2bf(b) << 16);
}

#define MFMA16(a, b, c) __builtin_amdgcn_mfma_f32_16x16x32_bf16((a), (b), (c), 0, 0, 0)

// swizzled LDS tile access: tiles are [rows][64] bf16 (128 B rows), byte ^= ((row&7)<<4)
__device__ __forceinline__ bf16x8 lds_rd8(const short* base, int row, int cb) {
    return *(const bf16x8*)((const char*)base + (((row) * 128 + (cb)) ^ (((row) & 7) << 4)));
}

// ---------------- K1: merged front-end ----------------
// bid 0..63: rope tables | bid 64: mask probe | bid 65..640: weight transpose+convert
// bid 641..3712: x fp32->bf16 convert.
__global__ __launch_bounds__(256) void prep_all_kernel(
    const float* __restrict__ x, short* __restrict__ xb,
    const float* __restrict__ Wq, const float* __restrict__ Wk,
    const float* __restrict__ Wv, const float* __restrict__ Wo,
    short* __restrict__ Wqt, short* __restrict__ Wkt,
    short* __restrict__ Wvt, short* __restrict__ Wot,
    float* __restrict__ cos_t, float* __restrict__ sin_t,
    const unsigned char* __restrict__ m, int* __restrict__ flag) {
    const int bid = blockIdx.x;
    if (bid < 64) {
        int i = bid * 256 + threadIdx.x;
        int p = i >> 5, j = i & 31;
        float inv_freq = powf(10000.0f, -(float)j / 32.0f);
        float ang = (float)p * inv_freq;
        cos_t[i] = cosf(ang);
        sin_t[i] = sinf(ang);
        return;
    }
    if (bid == 64) {   // probe: byte storage has nonzero bytes at offsets %4 != 0
        __shared__ int any;
        if (threadIdx.x == 0) any = 0;
        __syncthreads();
        int acc = 0;
        for (int i = threadIdx.x; i < NB * NS; i += 256)
            if ((i & 3) && m[i]) acc = 1;
        if (acc) atomicOr(&any, 1);
        __syncthreads();
        if (threadIdx.x == 0) *flag = any;   // 1 = byte storage, 0 = int32 storage
        return;
    }
    if (bid < 641) {   // weight transpose: W[k][n] fp32 -> Wt[n][k] bf16
        int idx = bid - 65;
        int zz = idx / 144, r2 = idx % 144;
        const float* W  = (zz == 0) ? Wq  : (zz == 1) ? Wk  : (zz == 2) ? Wv  : Wo;
        short*       Wt = (zz == 0) ? Wqt : (zz == 1) ? Wkt : (zz == 2) ? Wvt : Wot;
        const int k0 = (r2 / 12) * 64, n0 = (r2 % 12) * 64;
        __shared__ float t[64][65];
        for (int u = threadIdx.x; u < 4096; u += 256) {
            int r = u >> 6, c = u & 63;
            t[r][c] = W[(size_t)(k0 + r) * 768 + n0 + c];
        }
        __syncthreads();
        for (int u = threadIdx.x; u < 4096; u += 256) {
            int c = u >> 6, r = u & 63;
            Wt[(size_t)(n0 + c) * 768 + k0 + r] = f2bf(t[r][c]);
        }
        return;
    }
    int i = ((bid - 641) * 256 + threadIdx.x) * 8;   // convert x
    float4 a = *(const float4*)&x[i];
    float4 b = *(const float4*)&x[i + 4];
    bf16x8 r = { f2bf(a.x), f2bf(a.y), f2bf(a.z), f2bf(a.w),
                 f2bf(b.x), f2bf(b.y), f2bf(b.z), f2bf(b.w) };
    *(bf16x8*)&xb[i] = r;
}

// ---------------- K4: QKV projection GEMM (64x128, 2-phase pipelined, XCD-swizzled) ----------------
// flat grid 2304: xcd owns 16 m-panels x 18 (n,z) tiles. (Proven best config, r11/r14.)
__global__ __launch_bounds__(256) void gemm_qkv_kernel(const short* __restrict__ xb,
    const short* __restrict__ Wqt, const short* __restrict__ Wkt, const short* __restrict__ Wvt,
    const float* __restrict__ cos_t, const float* __restrict__ sin_t,
    short* __restrict__ qo, short* __restrict__ ko, short* __restrict__ kpo,
    short* __restrict__ vto) {
    const int id = blockIdx.x;
    const int xcd = id & 7, rest = id >> 3;   // rest 0..287
    const int mq = rest / 18;                 // 0..15
    const int nz = rest % 18;
    const int z  = nz / 6;
    const int n0 = (nz % 6) * 128;
    const int m0 = (xcd * 16 + mq) * 64;
    const short* Bt = (z == 0) ? Wqt : (z == 1) ? Wkt : Wvt;
    short*       O  = (z == 0) ? qo  : (z == 1) ? ko  : vto;
    __shared__ short As[2][64 * 64], Bs[2][128 * 64];   // 48 KB double-buffered
    const int tid = threadIdx.x, lane = tid & 63, wave = tid >> 6;
    const int g = lane >> 4, l15 = lane & 15;
    const int wm = wave >> 1, wn = wave & 1;
    f32x4 acc[2][4];
    #pragma unroll
    for (int i = 0; i < 2; ++i)
        #pragma unroll
        for (int j = 0; j < 4; ++j) acc[i][j] = (f32x4){0.f, 0.f, 0.f, 0.f};

    auto STAGE = [&](short* Ad, short* Bd, int kt) {
        const char* Asrc = (const char*)(xb + (size_t)m0 * 768 + kt * 64);
        const char* Bsrc = (const char*)(Bt + (size_t)n0 * 768 + kt * 64);
        #pragma unroll
        for (int p = 0; p < 2; ++p) {
            int dstoff = (wave * 2 + p) * 1024;
            int off = dstoff + lane * 16;
            int row = off >> 7, slot = off & 127;
            int srcs = slot ^ ((row & 7) << 4);
            __builtin_amdgcn_global_load_lds(AS1(Asrc + (size_t)row * 1536 + srcs),
                                             AS3((char*)Ad + dstoff), 16, 0, 0);
        }
        #pragma unroll
        for (int p = 0; p < 4; ++p) {
            int dstoff = (wave * 4 + p) * 1024;
            int off = dstoff + lane * 16;
            int row = off >> 7, slot = off & 127;
            int srcs = slot ^ ((row & 7) << 4);
            __builtin_amdgcn_global_load_lds(AS1(Bsrc + (size_t)row * 1536 + srcs),
                                             AS3((char*)Bd + dstoff), 16, 0, 0);
        }
    };
    auto COMPUTE = [&](const short* Asb, const short* Bsb) {
        __builtin_amdgcn_s_setprio(1);
        #pragma unroll
        for (int h2 = 0; h2 < 2; ++h2) {
            bf16x8 af[2], bfr[4];
            const int cb = h2 * 64 + g * 16;
            #pragma unroll
            for (int i = 0; i < 2; ++i)
                af[i]  = lds_rd8(Asb, wm * 32 + i * 16 + l15, cb);
            #pragma unroll
            for (int j = 0; j < 4; ++j)
                bfr[j] = lds_rd8(Bsb, wn * 64 + j * 16 + l15, cb);
            #pragma unroll
            for (int i = 0; i < 2; ++i)
                #pragma unroll
                for (int j = 0; j < 4; ++j)
                    acc[i][j] = MFMA16(af[i], bfr[j], acc[i][j]);
        }
        __builtin_amdgcn_s_setprio(0);
    };

    STAGE(As[0], Bs[0], 0);
    asm volatile("s_waitcnt vmcnt(0)" ::: "memory");
    __builtin_amdgcn_s_barrier();
    int cur = 0;
    for (int kt = 0; kt < 11; ++kt) {
        STAGE(As[cur ^ 1], Bs[cur ^ 1], kt + 1);   // next-tile loads in flight
        COMPUTE(As[cur], Bs[cur]);                 // hide load latency under MFMA
        asm volatile("s_waitcnt vmcnt(0)" ::: "memory");
        __builtin_amdgcn_s_barrier();
        cur ^= 1;
    }
    COMPUTE(As[cur], Bs[cur]);

    const int hh = (n0 + wn * 64) >> 6;   // head index (64-col wave-half = one head)
    #pragma unroll
    for (int i = 0; i < 2; ++i)
        #pragma unroll
        for (int r = 0; r < 4; ++r) {
            int mm = m0 + wm * 32 + i * 16 + g * 4 + r;
            int bb = mm >> 9, ss = mm & 511;
            if (z == 2) {   // V -> (b,h,d,s)
                #pragma unroll
                for (int j = 0; j < 4; ++j) {
                    int dd = j * 16 + l15;
                    O[(((size_t)bb * NH + hh) * ND + dd) * NS + ss] = f2bf(acc[i][j][r]);
                }
            } else {
                size_t base = (((size_t)bb * NH + hh) * NS + ss) * ND;
                #pragma unroll
                for (int j = 0; j < 4; ++j)
                    O[base + j * 16 + l15] = f2bf(acc[i][j][r]);
                if (z == 1) {   // roped K from pairs (j, j+2) = (d, d+32)
                    #pragma unroll
                    for (int p2 = 0; p2 < 2; ++p2) {
                        int jf = p2 * 16 + l15;
                        float c = cos_t[ss * 32 + jf], s = sin_t[ss * 32 + jf];
                        float t1 = acc[i][p2][r], t2 = acc[i][p2 + 2][r];
                        kpo[base + jf]      = f2bf(t1 * c - t2 * s);
                        kpo[base + 32 + jf] = f2bf(t1 * s + t2 * c);
                    }
                }
            }
        }
}

// ---------------- K6: fused chain-aware flash attention (T14 async-STAGE split) ----------------
// Next K/V tile prefetched into registers; issue moved BEFORE the post-write barrier
// so HBM latency also hides under the barrier wait (r16 micro-reorder).
__global__ __launch_bounds__(256) void attn_fused_kernel(
    const short* __restrict__ qr, const short* __restrict__ kr, const short* __restrict__ kp,
    const short* __restrict__ vt,
    const float* __restrict__ cos_t, const float* __restrict__ sin_t,
    const int* __restrict__ chain, const void* __restrict__ amask,
    const int* __restrict__ mflag, short* __restrict__ aout) {
    const int lid = blockIdx.x;
    const int xcd = lid & 7, idx = lid >> 3;
    const int qt = idx & 7, bhl = idx >> 3;
    const int bh = xcd * 24 + bhl;
    const int b = bh / 12, h = bh - (bh / 12) * 12;
    const int q0 = qt * 64;

    __shared__ short Kr_s[4096];
    __shared__ short Kp_s[4096];
    __shared__ short Vt_s[4096];
    __shared__ short P_s[4096];
    __shared__ int   ck_a[512];
    __shared__ float kb_a[512];

    const int tid = threadIdx.x, lane = tid & 63, wave = tid >> 6;
    const int g = lane >> 4, l15 = lane & 15;
    const int m_u8 = *mflag;
    const size_t bhNS = (size_t)bh * NS;
    const float SC = 0.18033688011f;   // 0.125 * log2(e)

    for (int u = tid; u < NS; u += 256) {
        int gidx = b * NS + u;
        ck_a[u] = chain[gidx];
        int ok = m_u8 ? (int)((const unsigned char*)amask)[gidx] : ((const int*)amask)[gidx];
        kb_a[u] = ok ? 0.f : -INFINITY;
    }
    const char* qrsC = (const char*)(qr + (bhNS + q0) * ND);
    #pragma unroll
    for (int p = 0; p < 2; ++p) {
        int dstoff = (wave * 2 + p) * 1024;
        int off = dstoff + lane * 16;
        int row = off >> 7, slot = off & 127;
        int srcs = slot ^ ((row & 7) << 4);
        __builtin_amdgcn_global_load_lds(AS1(qrsC + (size_t)row * 128 + srcs),
                                         AS3((char*)Kr_s + dstoff), 16, 0, 0);
    }
    __syncthreads();
    const int qrow = wave * 16 + l15;
    bf16x8 fqr0 = lds_rd8(Kr_s, qrow, g * 16);
    bf16x8 fqr1 = lds_rd8(Kr_s, qrow, 64 + g * 16);
    bf16x8 fqp0, fqp1;
    {
        int pos = q0 + qrow;
        float4 c0 = *(const float4*)&cos_t[pos * 32 + g * 8];
        float4 c1 = *(const float4*)&cos_t[pos * 32 + g * 8 + 4];
        float4 s0 = *(const float4*)&sin_t[pos * 32 + g * 8];
        float4 s1 = *(const float4*)&sin_t[pos * 32 + g * 8 + 4];
        float cc[8] = {c0.x, c0.y, c0.z, c0.w, c1.x, c1.y, c1.z, c1.w};
        float ss[8] = {s0.x, s0.y, s0.z, s0.w, s1.x, s1.y, s1.z, s1.w};
        #pragma unroll
        for (int j = 0; j < 8; ++j) {
            float t1 = bf2f(fqr0[j]), t2 = bf2f(fqr1[j]);
            fqp0[j] = f2bf(t1 * cc[j] - t2 * ss[j]);
            fqp1[j] = f2bf(t1 * ss[j] + t2 * cc[j]);
        }
    }
    const int cqv = ck_a[q0 + qrow];

    float m_run = -INFINITY, l_run = 0.f;
    f32x4 accO[4];
    #pragma unroll
    for (int t = 0; t < 4; ++t) accO[t] = (f32x4){0.f, 0.f, 0.f, 0.f};

    const char* krC = (const char*)(kr + bhNS * ND);
    const char* kpC = (const char*)(kp + bhNS * ND);
    const char* vtC = (const char*)(vt + bhNS * ND);

    int off_[2], row_[2], srcs_[2];
    #pragma unroll
    for (int p = 0; p < 2; ++p) {
        int dstoff = (wave * 2 + p) * 1024;
        off_[p]  = dstoff + lane * 16;
        row_[p]  = off_[p] >> 7;
        srcs_[p] = (off_[p] & 127) ^ ((row_[p] & 7) << 4);
    }
    uint4 rK0, rK1, rP0, rP1, rV0, rV1;   // named (rule #20: static indexing)
    uint4 nK0, nK1, nP0, nP1, nV0, nV1;   // next-tile prefetch regs
    auto LOADREGS = [&](int kv) {
        const int k0s = kv * 64;
        nK0 = *(const uint4*)(krC + (size_t)(k0s + row_[0]) * 128 + srcs_[0]);
        nK1 = *(const uint4*)(krC + (size_t)(k0s + row_[1]) * 128 + srcs_[1]);
        nP0 = *(const uint4*)(kpC + (size_t)(k0s + row_[0]) * 128 + srcs_[0]);
        nP1 = *(const uint4*)(kpC + (size_t)(k0s + row_[1]) * 128 + srcs_[1]);
        nV0 = *(const uint4*)(vtC + (size_t)row_[0] * 1024 + (size_t)k0s * 2 + srcs_[0]);
        nV1 = *(const uint4*)(vtC + (size_t)row_[1] * 1024 + (size_t)k0s * 2 + srcs_[1]);
    };
    auto WRITELDS = [&]() {
        *(uint4*)((char*)Kr_s + off_[0]) = rK0;
        *(uint4*)((char*)Kr_s + off_[1]) = rK1;
        *(uint4*)((char*)Kp_s + off_[0]) = rP0;
        *(uint4*)((char*)Kp_s + off_[1]) = rP1;
        *(uint4*)((char*)Vt_s + off_[0]) = rV0;
        *(uint4*)((char*)Vt_s + off_[1]) = rV1;
    };

    LOADREGS(0);
    rK0 = nK0; rK1 = nK1; rP0 = nP0; rP1 = nP1; rV0 = nV0; rV1 = nV1;
    __syncthreads();   // all waves done reading Q frags from Kr_s

    for (int kv = 0; kv < 8; ++kv) {
        const int k0s = kv * 64;
        WRITELDS();                      // waits on current-tile load regs
        if (kv < 7) LOADREGS(kv + 1);    // issue next loads BEFORE barrier wait
        __syncthreads();                 // tiles visible to all waves

        float pm[4][4];
        float tm = -INFINITY;
        __builtin_amdgcn_s_setprio(1);
        #pragma unroll
        for (int t = 0; t < 4; ++t) {
            bf16x8 akr0 = lds_rd8(Kr_s, t * 16 + l15, g * 16);
            bf16x8 akr1 = lds_rd8(Kr_s, t * 16 + l15, 64 + g * 16);
            bf16x8 akp0 = lds_rd8(Kp_s, t * 16 + l15, g * 16);
            bf16x8 akp1 = lds_rd8(Kp_s, t * 16 + l15, 64 + g * 16);
            f32x4 sr = (f32x4){0.f, 0.f, 0.f, 0.f};
            f32x4 sp = (f32x4){0.f, 0.f, 0.f, 0.f};
            sr = MFMA16(akr0, fqr0, sr);
            sr = MFMA16(akr1, fqr1, sr);
            sp = MFMA16(akp0, fqp0, sp);
            sp = MFMA16(akp1, fqp1, sp);
            int4   ck4 = *(const int4*)&ck_a[k0s + t * 16 + g * 4];
            float4 kb4 = *(const float4*)&kb_a[k0s + t * 16 + g * 4];
            const int   ckk[4] = {ck4.x, ck4.y, ck4.z, ck4.w};
            const float kbb[4] = {kb4.x, kb4.y, kb4.z, kb4.w};
            #pragma unroll
            for (int r = 0; r < 4; ++r) {
                float sv = (cqv == ckk[r]) ? sp[r] : sr[r];
                sv = sv * SC + kbb[r];
                pm[t][r] = sv;
                tm = fmaxf(tm, sv);
            }
        }
        __builtin_amdgcn_s_setprio(0);

        tm = fmaxf(tm, __shfl_xor(tm, 16));
        tm = fmaxf(tm, __shfl_xor(tm, 32));
        bool skip = __all(tm - m_run <= 8.f);
        float mnew, fac;
        if (skip) { mnew = m_run; fac = 1.f; }
        else      { mnew = fmaxf(m_run, tm); fac = exp2f(m_run - mnew); }
        float psum = 0.f;
        if (mnew == -INFINITY) {
            #pragma unroll
            for (int t = 0; t < 4; ++t)
                #pragma unroll
                for (int r = 0; r < 4; ++r) pm[t][r] = 0.f;
            fac = 1.f;
        } else {
            #pragma unroll
            for (int t = 0; t < 4; ++t)
                #pragma unroll
                for (int r = 0; r < 4; ++r) {
                    float p = exp2f(pm[t][r] - mnew);
                    pm[t][r] = p;
                    psum += p;
                }
        }
        psum += __shfl_xor(psum, 16);
        psum += __shfl_xor(psum, 32);
        l_run = l_run * fac + psum;
        m_run = mnew;

        char* pwave = (char*)P_s + wave * 2048;
        int psw = (l15 & 7) << 4;
        #pragma unroll
        for (int t = 0; t < 4; ++t) {
            unsigned u0 = pkbf2(pm[t][0], pm[t][1]);
            unsigned u1 = pkbf2(pm[t][2], pm[t][3]);
            uint2 pk = {u0, u1};
            *(uint2*)(pwave + ((l15 * 128 + t * 32 + g * 8) ^ psw)) = pk;
        }
        if (!skip) {
            float f4[4];
            #pragma unroll
            for (int r = 0; r < 4; ++r) f4[r] = __shfl(fac, g * 4 + r);
            #pragma unroll
            for (int t = 0; t < 4; ++t) {
                f32x4 a = accO[t];
                a[0] *= f4[0]; a[1] *= f4[1]; a[2] *= f4[2]; a[3] *= f4[3];
                accO[t] = a;
            }
        }
        bf16x8 pa0 = *(const bf16x8*)(pwave + ((l15 * 128 + g * 16) ^ psw));
        bf16x8 pa1 = *(const bf16x8*)(pwave + ((l15 * 128 + 64 + g * 16) ^ psw));
        __builtin_amdgcn_s_setprio(1);
        #pragma unroll
        for (int dt = 0; dt < 4; ++dt) {
            bf16x8 vb0 = lds_rd8(Vt_s, dt * 16 + l15, g * 16);
            bf16x8 vb1 = lds_rd8(Vt_s, dt * 16 + l15, 64 + g * 16);
            accO[dt] = MFMA16(pa0, vb0, accO[dt]);
            accO[dt] = MFMA16(pa1, vb1, accO[dt]);
        }
        __builtin_amdgcn_s_setprio(0);
        rK0 = nK0; rK1 = nK1; rP0 = nP0; rP1 = nP1; rV0 = nV0; rV1 = nV1;
        __syncthreads();   // all waves done reading tiles before next WRITELDS
    }

    float inv[4];
    #pragma unroll
    for (int r = 0; r < 4; ++r) {
        float lv = __shfl(l_run, g * 4 + r);
        inv[r] = (lv > 0.f) ? 1.f / lv : 0.f;
    }
    #pragma unroll
    for (int dt = 0; dt < 4; ++dt)
        #pragma unroll
        for (int r = 0; r < 4; ++r) {
            int row = b * NS + q0 + wave * 16 + g * 4 + r;
            aout[(size_t)row * NF + h * ND + dt * 16 + l15] = f2bf(accO[dt][r] * inv[r]);
        }
}

// ---------------- K7: output projection GEMM (64x128, 2-phase pipelined, XCD-swizzled) ----------------
__global__ __launch_bounds__(256) void gemm_out_kernel(const short* __restrict__ A,
    const short* __restrict__ Wot, float* __restrict__ out) {
    const int id = blockIdx.x;
    const int xcd = id & 7, rest = id >> 3;   // rest 0..95
    const int mq = rest / 6;                  // 0..15
    const int n0 = (rest % 6) * 128;
    const int m0 = (xcd * 16 + mq) * 64;
    __shared__ short As[2][64 * 64], Bs[2][128 * 64];   // 48 KB
    const int tid = threadIdx.x, lane = tid & 63, wave = tid >> 6;
    const int g = lane >> 4, l15 = lane & 15;
    const int wm = wave >> 1, wn = wave & 1;
    f32x4 acc[2][4];
    #pragma unroll
    for (int i = 0; i < 2; ++i)
        #pragma unroll
        for (int j = 0; j < 4; ++j) acc[i][j] = (f32x4){0.f, 0.f, 0.f, 0.f};

    auto STAGE = [&](short* Ad, short* Bd, int kt) {
        const char* Asrc = (const char*)(A   + (size_t)m0 * 768 + kt * 64);
        const char* Bsrc = (const char*)(Wot + (size_t)n0 * 768 + kt * 64);
        #pragma unroll
        for (int p = 0; p < 2; ++p) {
            int dstoff = (wave * 2 + p) * 1024;
            int off = dstoff + lane * 16;
            int row = off >> 7, slot = off & 127;
            int srcs = slot ^ ((row & 7) << 4);
            __builtin_amdgcn_global_load_lds(AS1(Asrc + (size_t)row * 1536 + srcs),
                                             AS3((char*)Ad + dstoff), 16, 0, 0);
        }
        #pragma unroll
        for (int p = 0; p < 4; ++p) {
            int dstoff = (wave * 4 + p) * 1024;
            int off = dstoff + lane * 16;
            int row = off >> 7, slot = off & 127;
            int srcs = slot ^ ((row & 7) << 4);
            __builtin_amdgcn_global_load_lds(AS1(Bsrc + (size_t)row * 1536 + srcs),
                                             AS3((char*)Bd + dstoff), 16, 0, 0);
        }
    };
    auto COMPUTE = [&](const short* Asb, const short* Bsb) {
        __builtin_amdgcn_s_setprio(1);
        #pragma unroll
        for (int h2 = 0; h2 < 2; ++h2) {
            bf16x8 af[2], bfr[4];
            const int cb = h2 * 64 + g * 16;
            #pragma unroll
            for (int i = 0; i < 2; ++i)
                af[i]  = lds_rd8(Asb, wm * 32 + i * 16 + l15, cb);
            #pragma unroll
            for (int j = 0; j < 4; ++j)
                bfr[j] = lds_rd8(Bsb, wn * 64 + j * 16 + l15, cb);
            #pragma unroll
            for (int i = 0; i < 2; ++i)
                #pragma unroll
                for (int j = 0; j < 4; ++j)
                    acc[i][j] = MFMA16(af[i], bfr[j], acc[i][j]);
        }
        __builtin_amdgcn_s_setprio(0);
    };

    STAGE(As[0], Bs[0], 0);
    asm volatile("s_waitcnt vmcnt(0)" ::: "memory");
    __builtin_amdgcn_s_barrier();
    int cur = 0;
    for (int kt = 0; kt < 11; ++kt) {
        STAGE(As[cur ^ 1], Bs[cur ^ 1], kt + 1);
        COMPUTE(As[cur], Bs[cur]);
        asm volatile("s_waitcnt vmcnt(0)" ::: "memory");
        __builtin_amdgcn_s_barrier();
        cur ^= 1;
    }
    COMPUTE(As[cur], Bs[cur]);

    #pragma unroll
    for (int i = 0; i < 2; ++i)
        #pragma unroll
        for (int r = 0; r < 4; ++r) {
            int mm = m0 + wm * 32 + i * 16 + g * 4 + r;
            #pragma unroll
            for (int j = 0; j < 4; ++j) {
                int n = n0 + wn * 64 + j * 16 + l15;
                out[(size_t)mm * NE + n] = acc[i][j][r];
            }
        }
}

extern "C" void kernel_launch(void* const* d_in, const int* in_sizes, int n_in,
                              void* d_out, int out_size, void* d_ws, size_t ws_size,
                              hipStream_t stream) {
    const float* x     = (const float*)d_in[0];
    const int*   chain = (const int*)d_in[1];
    const void*  amask = d_in[2];
    const float* Wq = (const float*)d_in[3];
    const float* Wk = (const float*)d_in[4];
    const float* Wv = (const float*)d_in[5];
    const float* Wo = (const float*)d_in[6];
    float* out = (float*)d_out;

    const size_t QSZ = (size_t)NB * NH * NS * ND;
    char* w = (char*)d_ws;
    float* cos_t = (float*)w;  w += (size_t)NS * 32 * 4;
    float* sin_t = (float*)w;  w += (size_t)NS * 32 * 4;
    int*   mflag = (int*)w;    w += 256;
    short* xb    = (short*)w;  w += (size_t)8192 * 768 * 2;  // reused as aout later
    short* Wqt   = (short*)w;  w += (size_t)768 * 768 * 2;
    short* Wkt   = (short*)w;  w += (size_t)768 * 768 * 2;
    short* Wvt   = (short*)w;  w += (size_t)768 * 768 * 2;
    short* Wot   = (short*)w;  w += (size_t)768 * 768 * 2;
    short* q_raw = (short*)w;  w += QSZ * 2;
    short* k_raw = (short*)w;  w += QSZ * 2;
    short* k_rop = (short*)w;  w += QSZ * 2;
    short* vtr   = (short*)w;  w += QSZ * 2;
    short* aout  = xb;   // lifetime-disjoint reuse

    prep_all_kernel<<<dim3(3713), dim3(256), 0, stream>>>(x, xb, Wq, Wk, Wv, Wo,
                                                          Wqt, Wkt, Wvt, Wot,
                                                          cos_t, sin_t,
                                                          (const unsigned char*)amask, mflag);
    gemm_qkv_kernel<<<dim3(2304), dim3(256), 0, stream>>>(xb, Wqt, Wkt, Wvt, cos_t, sin_t,
                                                          q_raw, k_raw, k_rop, vtr);
    attn_fused_kernel<<<dim3(1536), dim3(256), 0, stream>>>(q_raw, k_raw, k_rop, vtr,
                                                            cos_t, sin_t, chain, amask, mflag, aout);
    gemm_out_kernel<<<dim3(768), dim3(256), 0, stream>>>(aout, Wot, out);
}